// Round 3
// baseline (160.974 us; speedup 1.0000x reference)
//
#include <hip/hip_runtime.h>
#include <hip/hip_cooperative_groups.h>

namespace cg = cooperative_groups;

#define B_ 128
#define E_ 16
#define S_ 32768

constexpr int BLK   = 256;               // threads per block
constexpr int VPT   = 4;                 // float4s per thread
constexpr int CHUNK = BLK * VPT * 4;     // 4096 positions per block
constexpr int NCH   = S_ / CHUNK;        // 8 chunks per row
// grid = NCH x B_ = 1024 blocks = exactly 4 blocks/CU on 256 CUs

__global__ __launch_bounds__(BLK, 4) void fused_scatter_norm(
    const float* __restrict__ events, const int* __restrict__ indices,
    float* __restrict__ out, float* __restrict__ pmax)
{
    const int b  = blockIdx.y;
    const int cx = blockIdx.x;
    const int t  = (int)threadIdx.x;

    int p[VPT];
#pragma unroll
    for (int k = 0; k < VPT; ++k) p[k] = cx * CHUNK + 4 * (t + k * BLK);

    float4 acc[VPT] = {};

    const float* evb  = events + (size_t)b * (E_ * S_);
    const int*   idxb = indices + b * E_;

#pragma unroll
    for (int e = 0; e < E_; ++e) {
        const int off = idxb[e];                 // block-uniform scalar load
        const float* row = evb + e * S_ - off;   // row[p] == events[b,e,p-off]
#pragma unroll
        for (int k = 0; k < VPT; ++k) {
            const int s0 = p[k] - off;
            if (s0 >= 0) {                       // common: one dwordx4
                float4 v = *reinterpret_cast<const float4*>(row + p[k]);
                acc[k].x += v.x; acc[k].y += v.y;
                acc[k].z += v.z; acc[k].w += v.w;
            } else if (s0 > -4) {                // straddle: <=1 thread per (b,e)
                acc[k].w += row[p[k] + 3];       // s0>=-3 here, j=3 always valid
                if (s0 >= -2) acc[k].z += row[p[k] + 2];
                if (s0 >= -1) acc[k].y += row[p[k] + 1];
            }
        }
    }

    // ---- block max of the 16 per-thread sums ----
    float m = acc[0].x;
#pragma unroll
    for (int k = 0; k < VPT; ++k)
        m = fmaxf(m, fmaxf(fmaxf(acc[k].x, acc[k].y), fmaxf(acc[k].z, acc[k].w)));
#pragma unroll
    for (int d = 1; d < 64; d <<= 1)
        m = fmaxf(m, __shfl_xor(m, d, 64));

    __shared__ float wmax[BLK / 64];
    if ((t & 63) == 0) wmax[t >> 6] = m;
    __syncthreads();
    if (t == 0) {
        float mm = fmaxf(fmaxf(wmax[0], wmax[1]), fmaxf(wmax[2], wmax[3]));
        pmax[b * NCH + cx] = mm;                 // unique slot, no atomics
    }

    // ---- device-wide barrier (includes device-scope memory ordering) ----
    cg::this_grid().sync();

    // ---- per-row max, normalize in-register, single write ----
    const float* pm = pmax + b * NCH;
    float mr = pm[0];
#pragma unroll
    for (int c = 1; c < NCH; ++c) mr = fmaxf(mr, pm[c]);
    const float inv = 1.0f / (mr + 1e-8f);

    float* ob = out + (size_t)b * S_;
#pragma unroll
    for (int k = 0; k < VPT; ++k) {
        float4 v = acc[k];
        v.x *= inv; v.y *= inv; v.z *= inv; v.w *= inv;
        *reinterpret_cast<float4*>(ob + p[k]) = v;
    }
}

extern "C" void kernel_launch(void* const* d_in, const int* in_sizes, int n_in,
                              void* d_out, int out_size, void* d_ws, size_t ws_size,
                              hipStream_t stream) {
    const float* events  = (const float*)d_in[0];
    const int*   indices = (const int*)d_in[1];
    float* out  = (float*)d_out;
    float* pmax = (float*)d_ws;              // B_*NCH floats = 4 KB, rewritten every call

    dim3 grid(NCH, B_);
    dim3 block(BLK);
    void* args[] = {(void*)&events, (void*)&indices, (void*)&out, (void*)&pmax};
    hipLaunchCooperativeKernel((const void*)fused_scatter_norm, grid, block,
                               args, 0, stream);
}

// Round 4
// 145.818 us; speedup vs baseline: 1.1039x; 1.1039x over previous
//
#include <hip/hip_runtime.h>

#define B_ 128
#define E_ 16
#define S_ 32768

constexpr int BLK   = 256;               // threads per block
constexpr int VPT   = 4;                 // float4s per thread
constexpr int CHUNK = BLK * VPT * 4;     // 4096 positions per block
constexpr int NCH   = S_ / CHUNK;        // 8 chunks (blocks) per row
// grid = NCH x B_ = 1024 blocks = exactly 4 blocks/CU on 256 CUs

__global__ __launch_bounds__(BLK, 4) void fused_scatter_norm(
    const float* __restrict__ events, const int* __restrict__ indices,
    float* __restrict__ out, float* __restrict__ pmax, unsigned* __restrict__ cnt)
{
    const int b  = blockIdx.y;
    const int cx = blockIdx.x;
    const int t  = (int)threadIdx.x;

    int p[VPT];
#pragma unroll
    for (int k = 0; k < VPT; ++k) p[k] = cx * CHUNK + 4 * (t + k * BLK);

    float4 acc[VPT] = {};

    const float* evb  = events + (size_t)b * (E_ * S_);
    const int*   idxb = indices + b * E_;

#pragma unroll
    for (int e = 0; e < E_; ++e) {
        const int off = idxb[e];                 // block-uniform scalar load
        const float* row = evb + e * S_ - off;   // row[p] == events[b,e,p-off]
#pragma unroll
        for (int k = 0; k < VPT; ++k) {
            const int s0 = p[k] - off;
            if (s0 >= 0) {                       // common: one dwordx4
                float4 v = *reinterpret_cast<const float4*>(row + p[k]);
                acc[k].x += v.x; acc[k].y += v.y;
                acc[k].z += v.z; acc[k].w += v.w;
            } else if (s0 > -4) {                // straddle: <=1 thread per (b,e)
                acc[k].w += row[p[k] + 3];       // s0>=-3 => j=3 always valid
                if (s0 >= -2) acc[k].z += row[p[k] + 2];
                if (s0 >= -1) acc[k].y += row[p[k] + 1];
            }
        }
    }

    // ---- block max of the 16 per-thread sums ----
    float m = acc[0].x;
#pragma unroll
    for (int k = 0; k < VPT; ++k)
        m = fmaxf(m, fmaxf(fmaxf(acc[k].x, acc[k].y), fmaxf(acc[k].z, acc[k].w)));
#pragma unroll
    for (int d = 1; d < 64; d <<= 1)
        m = fmaxf(m, __shfl_xor(m, d, 64));

    __shared__ float wmax[BLK / 64];
    __shared__ float s_inv;
    if ((t & 63) == 0) wmax[t >> 6] = m;
    __syncthreads();

    if (t == 0) {
        float mm = fmaxf(fmaxf(wmax[0], wmax[1]), fmaxf(wmax[2], wmax[3]));
        // publish this block's partial max (device scope, release)
        __hip_atomic_store(&pmax[b * NCH + cx], mm,
                           __ATOMIC_RELEASE, __HIP_MEMORY_SCOPE_AGENT);
        // arrive at the per-row barrier
        __hip_atomic_fetch_add(&cnt[b], 1u,
                               __ATOMIC_ACQ_REL, __HIP_MEMORY_SCOPE_AGENT);
        // wait for all 8 blocks of this row (co-resident: cooperative launch)
        while (__hip_atomic_load(&cnt[b], __ATOMIC_ACQUIRE,
                                 __HIP_MEMORY_SCOPE_AGENT) < (unsigned)NCH)
            __builtin_amdgcn_s_sleep(16);
        // row max from the 8 partials (agent-scope loads: cross-XCD safe)
        float mr = -3.402823466e+38f;
#pragma unroll
        for (int c = 0; c < NCH; ++c)
            mr = fmaxf(mr, __hip_atomic_load(&pmax[b * NCH + c],
                                             __ATOMIC_RELAXED,
                                             __HIP_MEMORY_SCOPE_AGENT));
        s_inv = 1.0f / (mr + 1e-8f);
    }
    __syncthreads();
    const float inv = s_inv;

    // ---- normalize in-register, single output write ----
    float* ob = out + (size_t)b * S_;
#pragma unroll
    for (int k = 0; k < VPT; ++k) {
        float4 v = acc[k];
        v.x *= inv; v.y *= inv; v.z *= inv; v.w *= inv;
        *reinterpret_cast<float4*>(ob + p[k]) = v;
    }
}

extern "C" void kernel_launch(void* const* d_in, const int* in_sizes, int n_in,
                              void* d_out, int out_size, void* d_ws, size_t ws_size,
                              hipStream_t stream) {
    const float* events  = (const float*)d_in[0];
    const int*   indices = (const int*)d_in[1];
    float* out  = (float*)d_out;
    float*    pmax = (float*)d_ws;                    // B_*NCH floats = 4 KB
    unsigned* cnt  = (unsigned*)((char*)d_ws + B_ * NCH * sizeof(float)); // B_ uints

    // barrier counters must be zero at every call (ws not re-poisoned)
    hipMemsetAsync(cnt, 0, B_ * sizeof(unsigned), stream);

    dim3 grid(NCH, B_);
    dim3 block(BLK);
    void* args[] = {(void*)&events, (void*)&indices, (void*)&out,
                    (void*)&pmax, (void*)&cnt};
    hipLaunchCooperativeKernel((const void*)fused_scatter_norm, grid, block,
                               args, 0, stream);
}

// Round 5
// 145.474 us; speedup vs baseline: 1.1065x; 1.0024x over previous
//
#include <hip/hip_runtime.h>

#define B_ 128
#define E_ 16
#define S_ 32768

constexpr int BLK   = 256;               // threads per block
constexpr int CHUNK = 4096;              // positions per block (4 float4/thread)
constexpr int NCH   = S_ / CHUNK;        // 8 blocks per row
// grid = NCH x B_ = 1024 blocks = exactly 4 blocks/CU on 256 CUs

// One gather site: predicated dwordx4 accumulate into a NAMED float4 (no arrays
// anywhere -> rule #20: runtime-indexed ext_vector arrays go to scratch).
#define GATHER(A, P)                                                          \
    {                                                                         \
        const int s0_ = (P) - off;                                            \
        if (s0_ >= 0) {                                                       \
            float4 v_ = *reinterpret_cast<const float4*>(row + (P));          \
            A.x += v_.x; A.y += v_.y; A.z += v_.z; A.w += v_.w;               \
        } else if (s0_ > -4) {              /* straddle: rare scalar path */  \
            A.w += row[(P) + 3];            /* s0_>=-3 => +3 always valid */  \
            if (s0_ >= -2) A.z += row[(P) + 2];                               \
            if (s0_ >= -1) A.y += row[(P) + 1];                               \
        }                                                                     \
    }

__global__ __launch_bounds__(BLK, 4) void fused_scatter_norm(
    const float* __restrict__ events, const int* __restrict__ indices,
    float* __restrict__ out, float* __restrict__ pmax, unsigned* __restrict__ cnt)
{
    const int b  = blockIdx.y;
    const int cx = blockIdx.x;
    const int t  = (int)threadIdx.x;
    const int p0 = cx * CHUNK + 4 * t;     // this thread's 4 float4s:
                                           // p0, p0+1024, p0+2048, p0+3072
    float4 a0 = {0.f, 0.f, 0.f, 0.f};
    float4 a1 = {0.f, 0.f, 0.f, 0.f};
    float4 a2 = {0.f, 0.f, 0.f, 0.f};
    float4 a3 = {0.f, 0.f, 0.f, 0.f};

    const float* evb  = events + (size_t)b * (E_ * S_);
    const int*   idxb = indices + b * E_;

#pragma unroll 4
    for (int e = 0; e < E_; ++e) {
        const int off = idxb[e];                 // block-uniform scalar load
        const float* row = evb + e * S_ - off;   // row[p] == events[b,e,p-off]
        GATHER(a0, p0)
        GATHER(a1, p0 + 1024)
        GATHER(a2, p0 + 2048)
        GATHER(a3, p0 + 3072)
    }

    // ---- block max of the 16 per-thread sums ----
    float m = fmaxf(
        fmaxf(fmaxf(fmaxf(a0.x, a0.y), fmaxf(a0.z, a0.w)),
              fmaxf(fmaxf(a1.x, a1.y), fmaxf(a1.z, a1.w))),
        fmaxf(fmaxf(fmaxf(a2.x, a2.y), fmaxf(a2.z, a2.w)),
              fmaxf(fmaxf(a3.x, a3.y), fmaxf(a3.z, a3.w))));
#pragma unroll
    for (int d = 1; d < 64; d <<= 1)
        m = fmaxf(m, __shfl_xor(m, d, 64));

    __shared__ float wmax[BLK / 64];
    __shared__ float s_inv;
    if ((t & 63) == 0) wmax[t >> 6] = m;
    __syncthreads();

    if (t == 0) {
        float mm = fmaxf(fmaxf(wmax[0], wmax[1]), fmaxf(wmax[2], wmax[3]));
        // publish this block's partial max, then arrive at the per-row barrier
        __hip_atomic_store(&pmax[b * NCH + cx], mm,
                           __ATOMIC_RELEASE, __HIP_MEMORY_SCOPE_AGENT);
        __hip_atomic_fetch_add(&cnt[b], 1u,
                               __ATOMIC_ACQ_REL, __HIP_MEMORY_SCOPE_AGENT);
        while (__hip_atomic_load(&cnt[b], __ATOMIC_ACQUIRE,
                                 __HIP_MEMORY_SCOPE_AGENT) < (unsigned)NCH)
            __builtin_amdgcn_s_sleep(16);
        float mr = -3.402823466e+38f;
#pragma unroll
        for (int c = 0; c < NCH; ++c)
            mr = fmaxf(mr, __hip_atomic_load(&pmax[b * NCH + c],
                                             __ATOMIC_RELAXED,
                                             __HIP_MEMORY_SCOPE_AGENT));
        s_inv = 1.0f / (mr + 1e-8f);
    }
    __syncthreads();
    const float inv = s_inv;

    // ---- normalize in-register, single output write ----
    float* ob = out + (size_t)b * S_;
    a0.x *= inv; a0.y *= inv; a0.z *= inv; a0.w *= inv;
    a1.x *= inv; a1.y *= inv; a1.z *= inv; a1.w *= inv;
    a2.x *= inv; a2.y *= inv; a2.z *= inv; a2.w *= inv;
    a3.x *= inv; a3.y *= inv; a3.z *= inv; a3.w *= inv;
    *reinterpret_cast<float4*>(ob + p0)        = a0;
    *reinterpret_cast<float4*>(ob + p0 + 1024) = a1;
    *reinterpret_cast<float4*>(ob + p0 + 2048) = a2;
    *reinterpret_cast<float4*>(ob + p0 + 3072) = a3;
}

extern "C" void kernel_launch(void* const* d_in, const int* in_sizes, int n_in,
                              void* d_out, int out_size, void* d_ws, size_t ws_size,
                              hipStream_t stream) {
    const float* events  = (const float*)d_in[0];
    const int*   indices = (const int*)d_in[1];
    float* out  = (float*)d_out;
    float*    pmax = (float*)d_ws;                    // B_*NCH floats
    unsigned* cnt  = (unsigned*)((char*)d_ws + B_ * NCH * sizeof(float));

    // barrier counters must be zero at every call (ws not re-poisoned)
    hipMemsetAsync(cnt, 0, B_ * sizeof(unsigned), stream);

    dim3 grid(NCH, B_);
    dim3 block(BLK);
    void* args[] = {(void*)&events, (void*)&indices, (void*)&out,
                    (void*)&pmax, (void*)&cnt};
    hipLaunchCooperativeKernel((const void*)fused_scatter_norm, grid, block,
                               args, 0, stream);
}

// Round 6
// 46.924 us; speedup vs baseline: 3.4305x; 3.1002x over previous
//
#include <hip/hip_runtime.h>

#define B_ 128
#define E_ 16
#define S_ 32768

constexpr int BLK   = 256;               // threads per block (kernel A)
constexpr int CHUNK = 4096;              // positions per block (4 float4/thread)
constexpr int NCH   = S_ / CHUNK;        // 8 blocks per row

// Predicated dwordx4 gather-accumulate into a NAMED float4.
#define GATHER(A, P)                                                          \
    {                                                                         \
        const int s0_ = (P) - off;                                            \
        if (s0_ >= 0) {                                                       \
            float4 v_ = *reinterpret_cast<const float4*>(row + (P));          \
            A.x += v_.x; A.y += v_.y; A.z += v_.z; A.w += v_.w;               \
        } else if (s0_ > -4) {              /* straddle: rare scalar path */  \
            A.w += row[(P) + 3];            /* s0_>=-3 => +3 always valid */  \
            if (s0_ >= -2) A.z += row[(P) + 2];                               \
            if (s0_ >= -1) A.y += row[(P) + 1];                               \
        }                                                                     \
    }

__global__ __launch_bounds__(BLK) void gather_sum_max(
    const float* __restrict__ events, const int* __restrict__ indices,
    float* __restrict__ out, float* __restrict__ pmax)
{
    const int b  = blockIdx.y;
    const int cx = blockIdx.x;
    const int t  = (int)threadIdx.x;
    const int p0 = cx * CHUNK + 4 * t;   // this thread's 4 float4s

    float4 a0 = {0.f, 0.f, 0.f, 0.f};
    float4 a1 = {0.f, 0.f, 0.f, 0.f};
    float4 a2 = {0.f, 0.f, 0.f, 0.f};
    float4 a3 = {0.f, 0.f, 0.f, 0.f};

    const float* evb  = events + (size_t)b * (E_ * S_);
    const int*   idxb = indices + b * E_;

#pragma unroll 4
    for (int e = 0; e < E_; ++e) {
        const int off = idxb[e];                 // block-uniform scalar load
        const float* row = evb + e * S_ - off;   // row[p] == events[b,e,p-off]
        GATHER(a0, p0)
        GATHER(a1, p0 + 1024)
        GATHER(a2, p0 + 2048)
        GATHER(a3, p0 + 3072)
    }

    // raw sums out (single coalesced float4 stores)
    float* ob = out + (size_t)b * S_;
    *reinterpret_cast<float4*>(ob + p0)        = a0;
    *reinterpret_cast<float4*>(ob + p0 + 1024) = a1;
    *reinterpret_cast<float4*>(ob + p0 + 2048) = a2;
    *reinterpret_cast<float4*>(ob + p0 + 3072) = a3;

    // block max of the 16 per-thread sums
    float m = fmaxf(
        fmaxf(fmaxf(fmaxf(a0.x, a0.y), fmaxf(a0.z, a0.w)),
              fmaxf(fmaxf(a1.x, a1.y), fmaxf(a1.z, a1.w))),
        fmaxf(fmaxf(fmaxf(a2.x, a2.y), fmaxf(a2.z, a2.w)),
              fmaxf(fmaxf(a3.x, a3.y), fmaxf(a3.z, a3.w))));
#pragma unroll
    for (int d = 1; d < 64; d <<= 1)
        m = fmaxf(m, __shfl_xor(m, d, 64));

    __shared__ float wmax[BLK / 64];
    if ((t & 63) == 0) wmax[t >> 6] = m;
    __syncthreads();
    if (t == 0) {
        float mm = fmaxf(fmaxf(wmax[0], wmax[1]), fmaxf(wmax[2], wmax[3]));
        pmax[b * NCH + cx] = mm;   // unique slot: no memset, no atomics
    }
}

__global__ __launch_bounds__(256) void normalize_k(
    float* __restrict__ out, const float* __restrict__ pmax)
{
    const int b = blockIdx.y;
    const float* pm = pmax + b * NCH;      // 8 partials, L2-hot
    float m = fmaxf(fmaxf(fmaxf(pm[0], pm[1]), fmaxf(pm[2], pm[3])),
                    fmaxf(fmaxf(pm[4], pm[5]), fmaxf(pm[6], pm[7])));
    const float inv = 1.0f / (m + 1e-8f);

    // 2 float4s per thread; row has 8192 float4s; grid.x = 16 blocks/row
    const int i0 = blockIdx.x * 512 + (int)threadIdx.x;
    float4* o4 = reinterpret_cast<float4*>(out + (size_t)b * S_);

    float4 v = o4[i0];
    v.x *= inv; v.y *= inv; v.z *= inv; v.w *= inv;
    o4[i0] = v;

    float4 w = o4[i0 + 256];
    w.x *= inv; w.y *= inv; w.z *= inv; w.w *= inv;
    o4[i0 + 256] = w;
}

extern "C" void kernel_launch(void* const* d_in, const int* in_sizes, int n_in,
                              void* d_out, int out_size, void* d_ws, size_t ws_size,
                              hipStream_t stream) {
    const float* events  = (const float*)d_in[0];
    const int*   indices = (const int*)d_in[1];
    float* out  = (float*)d_out;
    float* pmax = (float*)d_ws;            // B_*NCH floats = 4 KB, all slots
                                           // rewritten by kernel A every call

    dim3 gridA(NCH, B_);                   // 8 x 128 = 1024 blocks
    gather_sum_max<<<gridA, BLK, 0, stream>>>(events, indices, out, pmax);

    dim3 gridB(16, B_);                    // 16 x 128 = 2048 blocks
    normalize_k<<<gridB, 256, 0, stream>>>(out, pmax);
}

// Round 7
// 39.081 us; speedup vs baseline: 4.1189x; 1.2007x over previous
//
#include <hip/hip_runtime.h>

#define B_ 128
#define E_ 16
#define S_ 32768

constexpr int BLK   = 256;              // threads per block (kernel A)
constexpr int CHUNK = BLK * 8;          // 2048 positions per block (2 float4/thread)
constexpr int NCH   = S_ / CHUNK;       // 16 chunks per batch row

// Unconditional clamped vector load + data-flow masking, so the compiler can
// hoist/batch the loads (a conditional load can't be speculated -> serializes).
// Straddle (partial vector) fixed up by a rare scalar branch.
#define GATHER(A, P)                                                          \
    {                                                                         \
        const int s_  = (P) - off;                                            \
        const int sc_ = s_ < 0 ? 0 : s_;        /* clamped: always in-bounds */\
        float4 v_ = *reinterpret_cast<const float4*>(rowbase + sc_);          \
        const float mk_ = s_ >= 0 ? 1.0f : 0.0f;                              \
        A.x = fmaf(v_.x, mk_, A.x);                                           \
        A.y = fmaf(v_.y, mk_, A.y);                                           \
        A.z = fmaf(v_.z, mk_, A.z);                                           \
        A.w = fmaf(v_.w, mk_, A.w);                                           \
        if (s_ > -4 && s_ < 0) {                /* straddle: 1 lane per (b,e) */\
            A.w += rowbase[(P) + 3 - off];      /* s_>=-3 => +3 valid */      \
            if (s_ >= -2) A.z += rowbase[(P) + 2 - off];                      \
            if (s_ >= -1) A.y += rowbase[(P) + 1 - off];                      \
        }                                                                     \
    }

__global__ __launch_bounds__(BLK) void gather_sum_max(
    const float* __restrict__ events, const int* __restrict__ indices,
    float* __restrict__ out, float* __restrict__ pmax)
{
    const int b  = blockIdx.y;
    const int t  = (int)threadIdx.x;
    const int pA = blockIdx.x * CHUNK + 4 * t;   // first float4 [pA..pA+3]
    const int pB = pA + 4 * BLK;                 // second float4

    float4 accA = {0.f, 0.f, 0.f, 0.f};
    float4 accB = {0.f, 0.f, 0.f, 0.f};

    const float* evb  = events + (size_t)b * (E_ * S_);
    const int*   idxb = indices + b * E_;

#pragma unroll 4
    for (int e = 0; e < E_; ++e) {
        const int off = idxb[e];                  // block-uniform scalar load
        const float* rowbase = evb + e * S_;      // events[b,e,0]
        GATHER(accA, pA)
        GATHER(accB, pB)
    }

    // aligned float4 stores of the raw sums
    float* ob = out + (size_t)b * S_;
    *reinterpret_cast<float4*>(ob + pA) = accA;
    *reinterpret_cast<float4*>(ob + pB) = accB;

    // thread-local max of the 8 values
    float m = fmaxf(fmaxf(fmaxf(accA.x, accA.y), fmaxf(accA.z, accA.w)),
                    fmaxf(fmaxf(accB.x, accB.y), fmaxf(accB.z, accB.w)));

    // 64-lane butterfly reduce
#pragma unroll
    for (int d = 1; d < 64; d <<= 1)
        m = fmaxf(m, __shfl_xor(m, d, 64));

    __shared__ float wmax[BLK / 64];
    if ((t & 63) == 0) wmax[t >> 6] = m;
    __syncthreads();
    if (t == 0) {
        float mm = fmaxf(fmaxf(wmax[0], wmax[1]), fmaxf(wmax[2], wmax[3]));
        pmax[b * NCH + blockIdx.x] = mm;   // unique slot: no memset, no atomics
    }
}

__global__ __launch_bounds__(256) void normalize_k(
    float* __restrict__ out, const float* __restrict__ pmax)
{
    const int b = blockIdx.y;
    // redundant per-block reduce of the 16 partial maxes (L2/L3-hot)
    const float* pm = pmax + b * NCH;
    float m = pm[0];
#pragma unroll
    for (int c = 1; c < NCH; ++c) m = fmaxf(m, pm[c]);
    const float inv = 1.0f / (m + 1e-8f);

    const int i = blockIdx.x * blockDim.x + threadIdx.x;   // float4 idx in row
    float4* o4 = reinterpret_cast<float4*>(out + (size_t)b * S_);
    float4 v = o4[i];
    v.x *= inv; v.y *= inv; v.z *= inv; v.w *= inv;
    o4[i] = v;
}

extern "C" void kernel_launch(void* const* d_in, const int* in_sizes, int n_in,
                              void* d_out, int out_size, void* d_ws, size_t ws_size,
                              hipStream_t stream) {
    const float* events  = (const float*)d_in[0];
    const int*   indices = (const int*)d_in[1];
    float* out  = (float*)d_out;
    float* pmax = (float*)d_ws;          // B_*NCH floats = 8 KB, fully rewritten
                                         // by kernel A every call

    dim3 gridA(NCH, B_);                 // 16 x 128 = 2048 blocks
    gather_sum_max<<<gridA, BLK, 0, stream>>>(events, indices, out, pmax);

    dim3 gridB(S_ / 4 / 256, B_);        // 32 x 128 = 4096 blocks
    normalize_k<<<gridB, 256, 0, stream>>>(out, pmax);
}

// Round 8
// 34.588 us; speedup vs baseline: 4.6540x; 1.1299x over previous
//
#include <hip/hip_runtime.h>

#define B_ 128
#define E_ 16
#define S_ 32768

constexpr int BLK   = 256;              // threads per block (kernel A)
constexpr int HALF  = 1024;             // contiguous positions per sub-chunk
constexpr int NCH   = S_ / (2 * HALF);  // 16 blocks per row (2 KB positions each)

// Unconditional clamped vector load + data-flow masking (R6, kept: compiler can
// hoist/batch). Straddle (partial vector) fixed by a rare scalar branch.
#define GATHER(A, P)                                                          \
    {                                                                         \
        const int s_  = (P) - off;                                            \
        const int sc_ = s_ < 0 ? 0 : s_;        /* clamped: always in-bounds */\
        float4 v_ = *reinterpret_cast<const float4*>(rowbase + sc_);          \
        const float mk_ = s_ >= 0 ? 1.0f : 0.0f;                              \
        A.x = fmaf(v_.x, mk_, A.x);                                           \
        A.y = fmaf(v_.y, mk_, A.y);                                           \
        A.z = fmaf(v_.z, mk_, A.z);                                           \
        A.w = fmaf(v_.w, mk_, A.w);                                           \
        if (s_ > -4 && s_ < 0) {                /* straddle: 1 lane per (b,e) */\
            A.w += rowbase[(P) + 3 - off];      /* s_>=-3 => +3 valid */      \
            if (s_ >= -2) A.z += rowbase[(P) + 2 - off];                      \
            if (s_ >= -1) A.y += rowbase[(P) + 1 - off];                      \
        }                                                                     \
    }

__global__ __launch_bounds__(BLK) void gather_sum_max(
    const float* __restrict__ events, const int* __restrict__ indices,
    float* __restrict__ out, float* __restrict__ pmax)
{
    const int b  = blockIdx.y;
    const int cx = blockIdx.x;
    const int t  = (int)threadIdx.x;

    // Reflection pairing for load balance: expected gather volume of the pair
    // {pA, pB} is ~constant in cx (forward chunk low half, mirrored chunk high
    // half), so every CU gets equal expected work regardless of block->CU maps.
    const int pA = cx * HALF + 4 * t;                 // [cx*1024, cx*1024+1024)
    const int pB = (S_ - HALF * (cx + 1)) + 4 * t;    // mirror chunk, 16B aligned

    float4 accA = {0.f, 0.f, 0.f, 0.f};
    float4 accB = {0.f, 0.f, 0.f, 0.f};

    const float* evb  = events + (size_t)b * (E_ * S_);
    const int*   idxb = indices + b * E_;

#pragma unroll 4
    for (int e = 0; e < E_; ++e) {
        const int off = idxb[e];                  // block-uniform scalar load
        const float* rowbase = evb + e * S_;      // events[b,e,0]
        GATHER(accA, pA)
        GATHER(accB, pB)
    }

    // aligned float4 stores of the raw sums
    float* ob = out + (size_t)b * S_;
    *reinterpret_cast<float4*>(ob + pA) = accA;
    *reinterpret_cast<float4*>(ob + pB) = accB;

    // thread-local max of the 8 values
    float m = fmaxf(fmaxf(fmaxf(accA.x, accA.y), fmaxf(accA.z, accA.w)),
                    fmaxf(fmaxf(accB.x, accB.y), fmaxf(accB.z, accB.w)));

    // 64-lane butterfly reduce
#pragma unroll
    for (int d = 1; d < 64; d <<= 1)
        m = fmaxf(m, __shfl_xor(m, d, 64));

    __shared__ float wmax[BLK / 64];
    if ((t & 63) == 0) wmax[t >> 6] = m;
    __syncthreads();
    if (t == 0) {
        float mm = fmaxf(fmaxf(wmax[0], wmax[1]), fmaxf(wmax[2], wmax[3]));
        pmax[b * NCH + cx] = mm;   // unique slot: no memset, no atomics
    }
}

__global__ __launch_bounds__(256) void normalize_k(
    float* __restrict__ out, const float* __restrict__ pmax)
{
    const int b = blockIdx.y;
    // redundant per-block reduce of the 16 partial maxes (L2/L3-hot)
    const float* pm = pmax + b * NCH;
    float m = pm[0];
#pragma unroll
    for (int c = 1; c < NCH; ++c) m = fmaxf(m, pm[c]);
    const float inv = 1.0f / (m + 1e-8f);

    const int i = blockIdx.x * blockDim.x + threadIdx.x;   // float4 idx in row
    float4* o4 = reinterpret_cast<float4*>(out + (size_t)b * S_);
    float4 v = o4[i];
    v.x *= inv; v.y *= inv; v.z *= inv; v.w *= inv;
    o4[i] = v;
}

extern "C" void kernel_launch(void* const* d_in, const int* in_sizes, int n_in,
                              void* d_out, int out_size, void* d_ws, size_t ws_size,
                              hipStream_t stream) {
    const float* events  = (const float*)d_in[0];
    const int*   indices = (const int*)d_in[1];
    float* out  = (float*)d_out;
    float* pmax = (float*)d_ws;          // B_*NCH floats = 8 KB, fully rewritten
                                         // by kernel A every call

    dim3 gridA(NCH, B_);                 // 16 x 128 = 2048 blocks
    gather_sum_max<<<gridA, BLK, 0, stream>>>(events, indices, out, pmax);

    dim3 gridB(S_ / 4 / 256, B_);        // 32 x 128 = 4096 blocks
    normalize_k<<<gridB, 256, 0, stream>>>(out, pmax);
}